// Round 6
// baseline (237.664 us; speedup 1.0000x reference)
//
#include <hip/hip_runtime.h>
#include <hip/hip_bf16.h>

#define T_STEPS 512
#define BATCH 32
#define NST 64
#define DIM 1024

typedef _Float16 f16x8 __attribute__((ext_vector_type(8)));
typedef _Float16 f16x4 __attribute__((ext_vector_type(4)));
typedef float f32x4 __attribute__((ext_vector_type(4)));
typedef float f32x2 __attribute__((ext_vector_type(2)));

__device__ __forceinline__ void gl_lds16(const void* g, void* l) {
  __builtin_amdgcn_global_load_lds(
      (const __attribute__((address_space(1))) void*)g,
      (__attribute__((address_space(3))) void*)l, 16, 0, 0);
}

// ---------------- W concat + fp16 convert ----------------
// Wc[256][1024] fp16, row order [Wk | Wq | Wv | Wa]. Wa pre-scaled by -log2(e)
// so the scan's sigmoid can use exp2 directly.
__global__ __launch_bounds__(256) void wconv(
    const float* __restrict__ Wk, const float* __restrict__ Wv,
    const float* __restrict__ Wq, const float* __restrict__ Wa,
    _Float16* __restrict__ Wc) {
  const int n = blockIdx.x;
  const int g = n >> 6, r = n & 63;
  const float* W = (g == 0) ? Wk : (g == 1) ? Wq : (g == 2) ? Wv : Wa;
  const float sc = (g == 3) ? -1.44269504088896340736f : 1.0f;
  float4 v = *(const float4*)(W + (size_t)r * DIM + threadIdx.x * 4);
  f16x4 h = {(_Float16)(v.x * sc), (_Float16)(v.y * sc), (_Float16)(v.z * sc),
             (_Float16)(v.w * sc)};
  *(f16x4*)(Wc + (size_t)n * DIM + threadIdx.x * 4) = h;
}

// ---------------- Projection GEMM v2 (fp32 output) ----------------
// BM=64, BN=256 (full width -> x read ONCE), BK=32.
// 256 blocks (1/CU), 512 threads = 8 waves (2/SIMD), wave grid 2m x 4n,
// wave tile 32m x 64n. A and B double-buffered in LDS, ONE barrier/K-step.
// projf[m][256] fp32, cols [k(64) | q(64) | v,ax interleaved(128)].
__global__ __launch_bounds__(512) void proj_gemm(
    const float* __restrict__ x, const _Float16* __restrict__ Wc,
    float* __restrict__ projf) {
  const int m0 = blockIdx.x * 64;
  const int tid = threadIdx.x;
  const int lane = tid & 63, wv = tid >> 6;
  const int wm = wv >> 2, wn = wv & 3;
  const int fm = lane & 15, fq = lane >> 4;

  __shared__ __align__(16) _Float16 Bl[2][256 * 32];  // 2 x 16 KB
  __shared__ __align__(16) _Float16 Al[2][64 * 32];   // 2 x 4 KB

  const int brow = tid >> 2;
  const int bcg = (tid & 3) ^ ((tid >> 3) & 3);
  const _Float16* gB = Wc + (size_t)brow * DIM + bcg * 8;
  const int bdst = tid * 8;

#define STAGE_B(buf, k0)                                          \
  {                                                               \
    _Pragma("unroll") for (int i = 0; i < 2; ++i)                 \
        gl_lds16(gB + (size_t)i * 128 * DIM + (k0),               \
                 &Bl[buf][i * 4096 + bdst]);                      \
  }

  const int arow = tid >> 3;
  const int afc = (tid & 7) * 4;
  const float* gA = x + (size_t)(m0 + arow) * DIM + afc;
  const int awp = arow * 32 + ((((tid >> 1) & 3) ^ ((arow >> 1) & 3)) * 8) +
                  (tid & 1) * 4;

#define LOADX(rr, k0)                          \
  {                                            \
    rr = *(const float4*)(gA + (k0));          \
  }
#define CVT_WRITE_A(buf, rr)                                        \
  {                                                                 \
    f16x4 h = {(_Float16)rr.x, (_Float16)rr.y, (_Float16)rr.z,      \
               (_Float16)rr.w};                                     \
    *(f16x4*)&Al[buf][awp] = h;                                     \
  }

  f32x4 acc[2][4];
#pragma unroll
  for (int mi = 0; mi < 2; ++mi)
#pragma unroll
    for (int ni = 0; ni < 4; ++ni) acc[mi][ni] = (f32x4){0.f, 0.f, 0.f, 0.f};

  const int aswz = (fq ^ ((fm >> 1) & 3)) * 8;
  const int abase = (wm * 32 + fm) * 32 + aswz;
  const int bbase = (wn * 64 + fm) * 32 + aswz;

#define COMPUTE(cb)                                                     \
  {                                                                     \
    f16x8 afr[2], bfr[4];                                               \
    _Pragma("unroll") for (int mi = 0; mi < 2; ++mi)                    \
        afr[mi] = *(const f16x8*)&Al[cb][abase + mi * 16 * 32];         \
    _Pragma("unroll") for (int ni = 0; ni < 4; ++ni)                    \
        bfr[ni] = *(const f16x8*)&Bl[cb][bbase + ni * 16 * 32];         \
    _Pragma("unroll") for (int mi = 0; mi < 2; ++mi)                    \
        _Pragma("unroll") for (int ni = 0; ni < 4; ++ni)                \
            acc[mi][ni] = __builtin_amdgcn_mfma_f32_16x16x32_f16(       \
                afr[mi], bfr[ni], acc[mi][ni], 0, 0, 0);                \
  }

  float4 rE, rO;
  LOADX(rE, 0);
  STAGE_B(0, 0);
  LOADX(rO, 32);
  CVT_WRITE_A(0, rE);
  __syncthreads();

  for (int k2 = 0; k2 < 16; ++k2) {
    STAGE_B(1, (2 * k2 + 1) * 32);
    if (k2 < 15) LOADX(rE, (2 * k2 + 2) * 32);
    CVT_WRITE_A(1, rO);
    COMPUTE(0);
    __syncthreads();
    if (k2 < 15) {
      STAGE_B(0, (2 * k2 + 2) * 32);
      LOADX(rO, (2 * k2 + 3) * 32);
      CVT_WRITE_A(0, rE);
    }
    COMPUTE(1);
    __syncthreads();
  }
#undef STAGE_B
#undef LOADX
#undef CVT_WRITE_A
#undef COMPUTE

  // C/D: col = lane&15, row = (lane>>4)*4 + reg. Remap cols: v,ax interleaved.
#pragma unroll
  for (int mi = 0; mi < 2; ++mi)
#pragma unroll
    for (int ni = 0; ni < 4; ++ni) {
      const int gcol = wn * 64 + ni * 16 + fm;
      const int pcol = gcol < 128 ? gcol
                     : (gcol < 192 ? 128 + 2 * (gcol - 128) : 129 + 2 * (gcol - 192));
#pragma unroll
      for (int r = 0; r < 4; ++r) {
        const int grow = m0 + wm * 32 + mi * 16 + fq * 4 + r;
        projf[(size_t)grow * 256 + pcol] = acc[mi][ni][r];
      }
    }
}

// ---------------- Sequential scan v3: chunk-register staging ----------------
// 128 blocks = (b, 16-row group rg), 512 threads = 8 waves.
// Producer (waves 0-3): recurrence only; loads 8 steps of {k, (v,ax)} per
// chunk DIRECTLY from global into registers (double-buffered, issued one
// phase ahead -> full phase of latency cover). Inner 8-step loop is PURE
// VALU/DPP: zero per-step memory ops. Writes {al, cc} to 2 KB LDS ring.
// Consumer (waves 4-7): same chunk-register staging of {k, q}; replays
// S = al*S + cc*k bit-identically one chunk behind, computes h, gated out.
// One barrier per phase (= per chunk per side).
__device__ __forceinline__ float red16(float x) {
  int v = __builtin_amdgcn_update_dpp(0, __float_as_int(x), 0xB1, 0xF, 0xF, true);
  x += __int_as_float(v);
  v = __builtin_amdgcn_update_dpp(0, __float_as_int(x), 0x4E, 0xF, 0xF, true);
  x += __int_as_float(v);
  v = __builtin_amdgcn_update_dpp(0, __float_as_int(x), 0x124, 0xF, 0xF, true);
  x += __int_as_float(v);
  v = __builtin_amdgcn_update_dpp(0, __float_as_int(x), 0x128, 0xF, 0xF, true);
  x += __int_as_float(v);
  return x;
}

__global__ __launch_bounds__(512, 1) void scan_kernel(
    const float* __restrict__ projf, const float* __restrict__ S0,
    const float* __restrict__ d_alpha, const float* __restrict__ b_alpha,
    float* __restrict__ out, float* __restrict__ Sout) {
  const int b = blockIdx.x >> 2;
  const int rg = blockIdx.x & 3;
  const int tid = threadIdx.x;
  const bool prod = tid < 256;
  const int ptid = tid & 255;
  const int c = ptid & 15;           // column lane
  const int lr = ptid >> 4;          // local row 0..15
  const int r = rg * 16 + lr;
  const int j0 = c * 4;

  __shared__ __align__(16) float2 alcc[2][16][8];  // [buf][row][step], 2 KB

  constexpr float NL2E = -1.44269504088896340736f;
  f32x2 s01, s23;
  {
    float4 v = *(const float4*)(S0 + ((size_t)b * NST + r) * NST + j0);
    s01 = (f32x2){v.x, v.y}; s23 = (f32x2){v.z, v.w};
  }
  const float da2 = d_alpha[r] * NL2E;
  const float ba2 = b_alpha[r] * NL2E;

  // projf row for step t, batch b: (t*32 + b)*256 floats. step stride 8192.
  const float* gb = projf + (size_t)b * 256;

  // ---- chunk-register load macros (8 steps -> regs), all-static indexing ----
#define P_LOAD(karr, varr, chn)                                         \
  {                                                                     \
    const float* pb = gb + (size_t)(chn) * 65536;                       \
    _Pragma("unroll") for (int si = 0; si < 8; ++si) {                  \
      karr[si] = *(const float4*)(pb + si * 8192 + j0);                 \
      varr[si] = *(const float2*)(pb + si * 8192 + 128 + 2 * r);        \
    }                                                                   \
  }
#define C_LOAD(karr, qarr, chn)                                         \
  {                                                                     \
    const float* pb = gb + (size_t)(chn) * 65536;                       \
    _Pragma("unroll") for (int si = 0; si < 8; ++si) {                  \
      karr[si] = *(const float4*)(pb + si * 8192 + j0);                 \
      qarr[si] = *(const float4*)(pb + si * 8192 + 64 + j0);            \
    }                                                                   \
  }

  // ---- pure-VALU 8-step bodies ----
#define P_COMP(karr, varr, abuf)                                        \
  {                                                                     \
    _Pragma("unroll") for (int si = 0; si < 8; ++si) {                  \
      const f32x2 k01 = {karr[si].x, karr[si].y};                       \
      const f32x2 k23 = {karr[si].z, karr[si].w};                       \
      f32x2 pa = s01 * k01 + s23 * k23;                                 \
      const float rr = red16(pa[0] + pa[1]);                            \
      float z2 = fmaf(da2, rr, varr[si].y + ba2);                       \
      z2 = __builtin_amdgcn_fmed3f(z2, -43.3f, 43.3f);                  \
      const float e = __builtin_amdgcn_exp2f(z2);                       \
      const float al = __builtin_amdgcn_rcpf(1.f + e);                  \
      const float ccv = (e * varr[si].x) * al;                          \
      const f32x2 al2 = {al, al}, cc2 = {ccv, ccv};                     \
      s01 = al2 * s01 + cc2 * k01;                                      \
      s23 = al2 * s23 + cc2 * k23;                                      \
      if (c == 0) alcc[abuf][lr][si] = make_float2(al, ccv);            \
    }                                                                   \
  }
#define C_COMP(karr, qarr, abuf, chn)                                   \
  {                                                                     \
    float2 acv[8];                                                      \
    _Pragma("unroll") for (int si = 0; si < 8; ++si)                    \
        acv[si] = alcc[abuf][lr][si];                                   \
    _Pragma("unroll") for (int si = 0; si < 8; ++si) {                  \
      const f32x2 k01 = {karr[si].x, karr[si].y};                       \
      const f32x2 k23 = {karr[si].z, karr[si].w};                       \
      const f32x2 al2 = {acv[si].x, acv[si].x};                         \
      const f32x2 cc2 = {acv[si].y, acv[si].y};                         \
      s01 = al2 * s01 + cc2 * k01;                                      \
      s23 = al2 * s23 + cc2 * k23;                                      \
      const f32x2 q01 = {qarr[si].x, qarr[si].y};                       \
      const f32x2 q23 = {qarr[si].z, qarr[si].w};                       \
      f32x2 hh = s01 * q01 + s23 * q23;                                 \
      const float h = red16(hh[0] + hh[1]);                             \
      if (c == 0) {                                                     \
        const float sg =                                                \
            __builtin_amdgcn_rcpf(1.f + __builtin_amdgcn_exp2f(h * NL2E)); \
        out[((size_t)((chn) * 8 + si) * BATCH + b) * NST + r] = (h * h) * sg; \
      }                                                                 \
    }                                                                   \
  }

  float4 kA[8], kB[8];   // producer: k ; consumer: k
  float2 vA[8], vB[8];   // producer only: (v, ax)
  float4 qA[8], qB[8];   // consumer only: q

  if (prod) {
    P_LOAD(kA, vA, 0);   // producer chunk 0 -> buf A (parity 0)
  }

  for (int c2 = 0; c2 < 32; ++c2) {
    // ---- phase A (phase index f = 2*c2, even) ----
    if (prod) {
      P_LOAD(kB, vB, 2 * c2 + 1);        // next chunk (odd -> B)
      P_COMP(kA, vA, 0);                 // compute chunk 2*c2, alcc buf0
    } else {
      C_LOAD(kA, qA, 2 * c2);            // load chunk 2*c2 (even -> A)
      if (c2 > 0) C_COMP(kB, qB, 1, 2 * c2 - 1);  // compute odd chunk, buf1
    }
    __syncthreads();
    // ---- phase B (phase index f = 2*c2+1, odd) ----
    if (prod) {
      if (c2 < 31) P_LOAD(kA, vA, 2 * c2 + 2);
      P_COMP(kB, vB, 1);                 // compute chunk 2*c2+1, alcc buf1
    } else {
      C_LOAD(kB, qB, 2 * c2 + 1);        // load chunk 2*c2+1 (odd -> B)
      C_COMP(kA, qA, 0, 2 * c2);         // compute even chunk, buf0
    }
    __syncthreads();
  }
  // epilogue: consumer computes final chunk 63 (odd -> B, alcc buf1)
  if (!prod) {
    C_COMP(kB, qB, 1, 63);
    float4 o = {s01[0], s01[1], s23[0], s23[1]};
    *(float4*)(Sout + ((size_t)b * NST + r) * NST + j0) = o;
  }
#undef P_LOAD
#undef C_LOAD
#undef P_COMP
#undef C_COMP
}

extern "C" void kernel_launch(void* const* d_in, const int* in_sizes, int n_in,
                              void* d_out, int out_size, void* d_ws, size_t ws_size,
                              hipStream_t stream) {
  const float* x  = (const float*)d_in[0];
  const float* S0 = (const float*)d_in[1];
  const float* Wk = (const float*)d_in[2];
  const float* Wv = (const float*)d_in[3];
  const float* Wq = (const float*)d_in[4];
  const float* Wa = (const float*)d_in[5];
  const float* da = (const float*)d_in[6];
  const float* ba = (const float*)d_in[7];

  float* out  = (float*)d_out;                        // [T,B,64]
  float* Sout = out + (size_t)T_STEPS * BATCH * NST;  // [B,64,64]
  float* projf = (float*)d_ws;                        // [16384][256] f32 = 16 MB
  _Float16* Wc = (_Float16*)((char*)d_ws + (size_t)16384 * 256 * 4);  // 512 KB

  wconv<<<256, 256, 0, stream>>>(Wk, Wv, Wq, Wa, Wc);
  proj_gemm<<<256, 512, 0, stream>>>(x, Wc, projf);
  scan_kernel<<<4 * BATCH, 512, 0, stream>>>(projf, S0, da, ba, out, Sout);
}

// Round 7
// 221.324 us; speedup vs baseline: 1.0738x; 1.0738x over previous
//
#include <hip/hip_runtime.h>
#include <hip/hip_bf16.h>

#define T_STEPS 512
#define BATCH 32
#define NST 64
#define DIM 1024

typedef _Float16 f16x8 __attribute__((ext_vector_type(8)));
typedef _Float16 f16x4 __attribute__((ext_vector_type(4)));
typedef float f32x4 __attribute__((ext_vector_type(4)));
typedef float f32x2 __attribute__((ext_vector_type(2)));

__device__ __forceinline__ void gl_lds16(const void* g, void* l) {
  __builtin_amdgcn_global_load_lds(
      (const __attribute__((address_space(1))) void*)g,
      (__attribute__((address_space(3))) void*)l, 16, 0, 0);
}

// ---------------- W concat + fp16 convert ----------------
// Wc[256][1024] fp16, row order [Wk | Wq | Wv | Wa]. Wa pre-scaled by -log2(e)
// so the scan's sigmoid can use exp2 directly.
__global__ __launch_bounds__(256) void wconv(
    const float* __restrict__ Wk, const float* __restrict__ Wv,
    const float* __restrict__ Wq, const float* __restrict__ Wa,
    _Float16* __restrict__ Wc) {
  const int n = blockIdx.x;
  const int g = n >> 6, r = n & 63;
  const float* W = (g == 0) ? Wk : (g == 1) ? Wq : (g == 2) ? Wv : Wa;
  const float sc = (g == 3) ? -1.44269504088896340736f : 1.0f;
  float4 v = *(const float4*)(W + (size_t)r * DIM + threadIdx.x * 4);
  f16x4 h = {(_Float16)(v.x * sc), (_Float16)(v.y * sc), (_Float16)(v.z * sc),
             (_Float16)(v.w * sc)};
  *(f16x4*)(Wc + (size_t)n * DIM + threadIdx.x * 4) = h;
}

// ---------------- Projection GEMM v2 (fp32 output) ----------------
// BM=64, BN=256 (full width -> x read ONCE), BK=32.
// 256 blocks (1/CU), 512 threads = 8 waves (2/SIMD), wave grid 2m x 4n,
// wave tile 32m x 64n. A and B double-buffered in LDS, ONE barrier/K-step.
// projf[m][256] fp32, cols [k(64) | q(64) | v,ax interleaved(128)].
__global__ __launch_bounds__(512) void proj_gemm(
    const float* __restrict__ x, const _Float16* __restrict__ Wc,
    float* __restrict__ projf) {
  const int m0 = blockIdx.x * 64;
  const int tid = threadIdx.x;
  const int lane = tid & 63, wv = tid >> 6;
  const int wm = wv >> 2, wn = wv & 3;
  const int fm = lane & 15, fq = lane >> 4;

  __shared__ __align__(16) _Float16 Bl[2][256 * 32];  // 2 x 16 KB
  __shared__ __align__(16) _Float16 Al[2][64 * 32];   // 2 x 4 KB

  const int brow = tid >> 2;
  const int bcg = (tid & 3) ^ ((tid >> 3) & 3);
  const _Float16* gB = Wc + (size_t)brow * DIM + bcg * 8;
  const int bdst = tid * 8;

#define STAGE_B(buf, k0)                                          \
  {                                                               \
    _Pragma("unroll") for (int i = 0; i < 2; ++i)                 \
        gl_lds16(gB + (size_t)i * 128 * DIM + (k0),               \
                 &Bl[buf][i * 4096 + bdst]);                      \
  }

  const int arow = tid >> 3;
  const int afc = (tid & 7) * 4;
  const float* gA = x + (size_t)(m0 + arow) * DIM + afc;
  const int awp = arow * 32 + ((((tid >> 1) & 3) ^ ((arow >> 1) & 3)) * 8) +
                  (tid & 1) * 4;

#define LOADX(rr, k0)                          \
  {                                            \
    rr = *(const float4*)(gA + (k0));          \
  }
#define CVT_WRITE_A(buf, rr)                                        \
  {                                                                 \
    f16x4 h = {(_Float16)rr.x, (_Float16)rr.y, (_Float16)rr.z,      \
               (_Float16)rr.w};                                     \
    *(f16x4*)&Al[buf][awp] = h;                                     \
  }

  f32x4 acc[2][4];
#pragma unroll
  for (int mi = 0; mi < 2; ++mi)
#pragma unroll
    for (int ni = 0; ni < 4; ++ni) acc[mi][ni] = (f32x4){0.f, 0.f, 0.f, 0.f};

  const int aswz = (fq ^ ((fm >> 1) & 3)) * 8;
  const int abase = (wm * 32 + fm) * 32 + aswz;
  const int bbase = (wn * 64 + fm) * 32 + aswz;

#define COMPUTE(cb)                                                     \
  {                                                                     \
    f16x8 afr[2], bfr[4];                                               \
    _Pragma("unroll") for (int mi = 0; mi < 2; ++mi)                    \
        afr[mi] = *(const f16x8*)&Al[cb][abase + mi * 16 * 32];         \
    _Pragma("unroll") for (int ni = 0; ni < 4; ++ni)                    \
        bfr[ni] = *(const f16x8*)&Bl[cb][bbase + ni * 16 * 32];         \
    _Pragma("unroll") for (int mi = 0; mi < 2; ++mi)                    \
        _Pragma("unroll") for (int ni = 0; ni < 4; ++ni)                \
            acc[mi][ni] = __builtin_amdgcn_mfma_f32_16x16x32_f16(       \
                afr[mi], bfr[ni], acc[mi][ni], 0, 0, 0);                \
  }

  float4 rE, rO;
  LOADX(rE, 0);
  STAGE_B(0, 0);
  LOADX(rO, 32);
  CVT_WRITE_A(0, rE);
  __syncthreads();

  for (int k2 = 0; k2 < 16; ++k2) {
    STAGE_B(1, (2 * k2 + 1) * 32);
    if (k2 < 15) LOADX(rE, (2 * k2 + 2) * 32);
    CVT_WRITE_A(1, rO);
    COMPUTE(0);
    __syncthreads();
    if (k2 < 15) {
      STAGE_B(0, (2 * k2 + 2) * 32);
      LOADX(rO, (2 * k2 + 3) * 32);
      CVT_WRITE_A(0, rE);
    }
    COMPUTE(1);
    __syncthreads();
  }
#undef STAGE_B
#undef LOADX
#undef CVT_WRITE_A
#undef COMPUTE

  // C/D: col = lane&15, row = (lane>>4)*4 + reg. Remap cols: v,ax interleaved.
#pragma unroll
  for (int mi = 0; mi < 2; ++mi)
#pragma unroll
    for (int ni = 0; ni < 4; ++ni) {
      const int gcol = wn * 64 + ni * 16 + fm;
      const int pcol = gcol < 128 ? gcol
                     : (gcol < 192 ? 128 + 2 * (gcol - 128) : 129 + 2 * (gcol - 192));
#pragma unroll
      for (int r = 0; r < 4; ++r) {
        const int grow = m0 + wm * 32 + mi * 16 + fq * 4 + r;
        projf[(size_t)grow * 256 + pcol] = acc[mi][ni][r];
      }
    }
}

// ---------------- Gram kernel: g[b][t] = k_{t-1} . k_t ----------------
// Pure-input scalar for the producer's lookahead. g[b][0] = 0.
__global__ __launch_bounds__(256) void gram_kernel(
    const float* __restrict__ projf, float* __restrict__ gmat) {
  const int b = blockIdx.x >> 1;
  const int t = (blockIdx.x & 1) * 256 + threadIdx.x;
  float acc = 0.f;
  if (t > 0) {
    const float* ka = projf + ((size_t)(t - 1) * BATCH + b) * 256;
    const float* kb = projf + ((size_t)t * BATCH + b) * 256;
#pragma unroll
    for (int j = 0; j < 64; j += 4) {
      float4 va = *(const float4*)(ka + j);
      float4 vb = *(const float4*)(kb + j);
      acc = fmaf(va.x, vb.x, acc);
      acc = fmaf(va.y, vb.y, acc);
      acc = fmaf(va.z, vb.z, acc);
      acc = fmaf(va.w, vb.w, acc);
    }
  }
  gmat[(size_t)b * T_STEPS + t] = acc;
}

// ---------------- Sequential scan v4: wave split + producer lookahead ------
// 128 blocks = (b, 16-row group rg), 512 threads = 8 waves.
// Staging: R5's cooperative LDS ring (4 chunks x 8 steps x 256 f32), all 512
// threads stage 1 float4/chunk, 1.5 chunks ahead (register prefetch across
// barriers is defeated by hipcc's vmcnt(0)-before-barrier -- R6 lesson).
// Producer (waves 0-3): recurrence with 1-step lookahead so the dot+red16 is
// OFF the carried chain:
//   rr_t = al_{t-1} * fma(e_{t-1}, v_{t-1}*g_t, u_t)
//   u_t  = S_{t-2}.k_t   (computed one step early, full step of slack)
//   g_t  = k_{t-1}.k_t   (precomputed gram scalar, staged in LDS)
// Carried chain/step: fma,mul,fma,med3,exp2,add,rcp,mul ~ 8 ops.
// Writes {al, cc} to 2 KB LDS ring. Consumer (waves 4-7): replays
// S = al*S + cc*k one chunk behind, computes h = S.q, gated out, Sout.
__device__ __forceinline__ float red16(float x) {
  int v = __builtin_amdgcn_update_dpp(0, __float_as_int(x), 0xB1, 0xF, 0xF, true);
  x += __int_as_float(v);
  v = __builtin_amdgcn_update_dpp(0, __float_as_int(x), 0x4E, 0xF, 0xF, true);
  x += __int_as_float(v);
  v = __builtin_amdgcn_update_dpp(0, __float_as_int(x), 0x124, 0xF, 0xF, true);
  x += __int_as_float(v);
  v = __builtin_amdgcn_update_dpp(0, __float_as_int(x), 0x128, 0xF, 0xF, true);
  x += __int_as_float(v);
  return x;
}

__global__ __launch_bounds__(512, 1) void scan_kernel(
    const float* __restrict__ projf, const float* __restrict__ gmat,
    const float* __restrict__ S0,
    const float* __restrict__ d_alpha, const float* __restrict__ b_alpha,
    float* __restrict__ out, float* __restrict__ Sout) {
  const int b = blockIdx.x >> 2;
  const int rg = blockIdx.x & 3;
  const int tid = threadIdx.x;
  const bool prod = tid < 256;
  const int ptid = tid & 255;
  const int c = ptid & 15;           // column lane
  const int lr = ptid >> 4;          // local row 0..15
  const int r = rg * 16 + lr;
  const int j0 = c * 4;

  __shared__ __align__(16) float lbuf[4][2048];    // 4-ring x (8 x 256) f32
  __shared__ __align__(16) float2 alcc[2][8][16];  // {al, cc} handoff, 2 KB
  __shared__ __align__(8) float glds[T_STEPS];     // gram row, 2 KB

  constexpr float NL2E = -1.44269504088896340736f;
  f32x2 s01, s23;
  {
    float4 v = *(const float4*)(S0 + ((size_t)b * NST + r) * NST + j0);
    s01 = (f32x2){v.x, v.y}; s23 = (f32x2){v.z, v.w};
  }
  const float da2 = d_alpha[r] * NL2E;
  const float ba2 = b_alpha[r] * NL2E;

  // staging: 512 threads x 1 float4 = one 8-step chunk (8 KB)
  const int sstep = tid >> 6;         // 0..7
  const int soff = (tid & 63) * 4;    // 0..252
  const int lidx = sstep * 256 + soff;
  const float* gp = projf + (size_t)b * 256;
#define GADDR(ch) (gp + (size_t)((ch) * 8 + sstep) * (BATCH * 256) + soff)

  glds[tid] = gmat[(size_t)b * T_STEPS + tid];  // 512 threads cover 512 steps

  float4 rA;
  rA = *(const float4*)GADDR(0); *(float4*)&lbuf[0][lidx] = rA;
  rA = *(const float4*)GADDR(1); *(float4*)&lbuf[1][lidx] = rA;
  rA = *(const float4*)GADDR(2);
  __syncthreads();

  // producer: 4-slot ring (distance-2 prefetch so k_{t+1} is never fresh)
  float4 kf[4];
  float2 vaf[4];
  float gv[4];
#define PREFP(tn)                                                        \
  {                                                                      \
    const int pp = (tn) & 3;                                             \
    const float* Pn = &lbuf[((tn) >> 3) & 3][((tn) & 7) * 256];          \
    kf[pp] = *(const float4*)(Pn + j0);                                  \
    vaf[pp] = *(const float2*)(Pn + 128 + 2 * r);                        \
    gv[pp] = glds[(tn)];                                                 \
  }
  // consumer: 2-slot ring
  float4 kc4[2], qc4[2];
#define PREFC(tn)                                                        \
  {                                                                      \
    const int pp = (tn) & 1;                                             \
    const float* Pn = &lbuf[((tn) >> 3) & 3][((tn) & 7) * 256];          \
    kc4[pp] = *(const float4*)(Pn + j0);                                 \
    qc4[pp] = *(const float4*)(Pn + 64 + j0);                            \
  }

  // producer carried state
  float al = 1.f, e = 0.f, vp = 0.f, u = 0.f;
  f32x2 cck01 = {0.f, 0.f}, cck23 = {0.f, 0.f};
  f32x2 kc01, kc23;

  if (prod) {
    PREFP(0);
    PREFP(1);
    kc01 = (f32x2){kf[0].x, kf[0].y};
    kc23 = (f32x2){kf[0].z, kf[0].w};
    f32x2 pa = s01 * kc01 + s23 * kc23;
    u = red16(pa[0] + pa[1]);  // u_0 = S_init . k_0
  } else {
    PREFC(0);
  }

  for (int ch = 0; ch <= 64; ++ch) {
    if (prod) {
      if (ch < 64) {
#pragma unroll
        for (int si = 0; si < 8; ++si) {
          const int t = ch * 8 + si;
          const int p = si & 3;        // == t & 3  (ch*8 ≡ 0 mod 4)
          const int pn = (si + 1) & 3; // == (t+1) & 3
          if (t + 2 < T_STEPS) PREFP(t + 2);

          const float vt = vaf[p].x, axv = vaf[p].y;

          // ---- carried chain: al_{t-1} -> al_t ----
          const float w = fmaf(e, vp * gv[p], u);  // vp*gv off-chain
          const float rr = al * w;                 // retrieved_t
          float z2 = fmaf(da2, rr, axv + ba2);
          z2 = __builtin_amdgcn_fmed3f(z2, -43.3f, 43.3f);
          const float eN = __builtin_amdgcn_exp2f(z2);         // exp(-z)
          const float alN = __builtin_amdgcn_rcpf(1.f + eN);   // sigmoid
          const float ccN = (eN * vt) * alN;                   // (1-al)*v

          // ---- S_{t-1} = al_{t-1}*S_{t-2} + cc_{t-1}*k_{t-1} ----
          const f32x2 al2 = {al, al};
          s01 = al2 * s01 + cck01;
          s23 = al2 * s23 + cck23;

          // ---- u_{t+1} = S_{t-1}.k_{t+1} (one step of slack) ----
          const f32x2 kn01 = {kf[pn].x, kf[pn].y};
          const f32x2 kn23 = {kf[pn].z, kf[pn].w};
          f32x2 ua = s01 * kn01 + s23 * kn23;
          const float uN = red16(ua[0] + ua[1]);

          if (c == 0) alcc[ch & 1][si][lr] = make_float2(alN, ccN);

          // ---- rotate carried state ----
          const f32x2 cc2 = {ccN, ccN};
          cck01 = cc2 * kc01; cck23 = cc2 * kc23;
          kc01 = kn01; kc23 = kn23;
          al = alN; e = eN; vp = vt; u = uN;
        }
      }
    } else {
      if (ch >= 1) {
        const int pch = ch - 1;
#pragma unroll
        for (int si = 0; si < 8; ++si) {
          const int t = pch * 8 + si;
          const int p = si & 1;  // == t & 1 (pch*8 even)
          if (t + 1 < T_STEPS) PREFC(t + 1);

          float2 ac = alcc[pch & 1][si][lr];  // broadcast read
          const f32x2 al2 = {ac.x, ac.x}, cc2 = {ac.y, ac.y};
          const f32x2 k01 = {kc4[p].x, kc4[p].y};
          const f32x2 k23 = {kc4[p].z, kc4[p].w};
          s01 = al2 * s01 + cc2 * k01;  // bit-identical S replay
          s23 = al2 * s23 + cc2 * k23;

          const f32x2 q01 = {qc4[p].x, qc4[p].y};
          const f32x2 q23 = {qc4[p].z, qc4[p].w};
          f32x2 hh = s01 * q01 + s23 * q23;
          const float h = red16(hh[0] + hh[1]);
          if (c == 0) {
            const float sg =
                __builtin_amdgcn_rcpf(1.f + __builtin_amdgcn_exp2f(h * NL2E));
            out[((size_t)t * BATCH + b) * NST + r] = (h * h) * sg;
          }
        }
      }
    }
    __syncthreads();  // alcc handoff; lbuf readers of retiring buffer done
    if (ch + 2 < 64) *(float4*)&lbuf[(ch + 2) & 3][lidx] = rA;
    if (ch + 3 < 64) rA = *(const float4*)GADDR(ch + 3);
    __syncthreads();  // staged chunk visible
  }
#undef PREFP
#undef PREFC
#undef GADDR

  if (!prod) {
    float4 o = {s01[0], s01[1], s23[0], s23[1]};
    *(float4*)(Sout + ((size_t)b * NST + r) * NST + j0) = o;
  }
}

extern "C" void kernel_launch(void* const* d_in, const int* in_sizes, int n_in,
                              void* d_out, int out_size, void* d_ws, size_t ws_size,
                              hipStream_t stream) {
  const float* x  = (const float*)d_in[0];
  const float* S0 = (const float*)d_in[1];
  const float* Wk = (const float*)d_in[2];
  const float* Wv = (const float*)d_in[3];
  const float* Wq = (const float*)d_in[4];
  const float* Wa = (const float*)d_in[5];
  const float* da = (const float*)d_in[6];
  const float* ba = (const float*)d_in[7];

  float* out  = (float*)d_out;                        // [T,B,64]
  float* Sout = out + (size_t)T_STEPS * BATCH * NST;  // [B,64,64]
  float* projf = (float*)d_ws;                        // [16384][256] f32 = 16 MB
  _Float16* Wc = (_Float16*)((char*)d_ws + (size_t)16384 * 256 * 4);  // 512 KB
  float* gmat = (float*)((char*)d_ws + (size_t)16384 * 256 * 4 + 512 * 1024);  // 64 KB

  wconv<<<256, 256, 0, stream>>>(Wk, Wv, Wq, Wa, Wc);
  proj_gemm<<<256, 512, 0, stream>>>(x, Wc, projf);
  gram_kernel<<<64, 256, 0, stream>>>(projf, gmat);
  scan_kernel<<<4 * BATCH, 512, 0, stream>>>(projf, gmat, S0, da, ba, out, Sout);
}

// Round 8
// 207.057 us; speedup vs baseline: 1.1478x; 1.0689x over previous
//
#include <hip/hip_runtime.h>
#include <hip/hip_bf16.h>

#define T_STEPS 512
#define BATCH 32
#define NST 64
#define DIM 1024

typedef _Float16 f16x8 __attribute__((ext_vector_type(8)));
typedef _Float16 f16x4 __attribute__((ext_vector_type(4)));
typedef float f32x4 __attribute__((ext_vector_type(4)));
typedef float f32x2 __attribute__((ext_vector_type(2)));

__device__ __forceinline__ void gl_lds16(const void* g, void* l) {
  __builtin_amdgcn_global_load_lds(
      (const __attribute__((address_space(1))) void*)g,
      (__attribute__((address_space(3))) void*)l, 16, 0, 0);
}

// ---------------- W concat + fp16 convert ----------------
// Wc[256][1024] fp16, row order [Wk | Wq | Wv | Wa]. Wa pre-scaled by -log2(e)
// so the scan's sigmoid can use exp2 directly.
__global__ __launch_bounds__(256) void wconv(
    const float* __restrict__ Wk, const float* __restrict__ Wv,
    const float* __restrict__ Wq, const float* __restrict__ Wa,
    _Float16* __restrict__ Wc) {
  const int n = blockIdx.x;
  const int g = n >> 6, r = n & 63;
  const float* W = (g == 0) ? Wk : (g == 1) ? Wq : (g == 2) ? Wv : Wa;
  const float sc = (g == 3) ? -1.44269504088896340736f : 1.0f;
  float4 v = *(const float4*)(W + (size_t)r * DIM + threadIdx.x * 4);
  f16x4 h = {(_Float16)(v.x * sc), (_Float16)(v.y * sc), (_Float16)(v.z * sc),
             (_Float16)(v.w * sc)};
  *(f16x4*)(Wc + (size_t)n * DIM + threadIdx.x * 4) = h;
}

// ---------------- Projection GEMM v2 (fp32 output) ----------------
// BM=64, BN=256 (full width -> x read ONCE), BK=32.
// 256 blocks (1/CU), 512 threads = 8 waves (2/SIMD), wave grid 2m x 4n,
// wave tile 32m x 64n. A and B double-buffered in LDS, ONE barrier/K-step.
// projf[m][256] fp32, cols [k(64) | q(64) | v,ax interleaved(128)].
__global__ __launch_bounds__(512) void proj_gemm(
    const float* __restrict__ x, const _Float16* __restrict__ Wc,
    float* __restrict__ projf) {
  const int m0 = blockIdx.x * 64;
  const int tid = threadIdx.x;
  const int lane = tid & 63, wv = tid >> 6;
  const int wm = wv >> 2, wn = wv & 3;
  const int fm = lane & 15, fq = lane >> 4;

  __shared__ __align__(16) _Float16 Bl[2][256 * 32];  // 2 x 16 KB
  __shared__ __align__(16) _Float16 Al[2][64 * 32];   // 2 x 4 KB

  const int brow = tid >> 2;
  const int bcg = (tid & 3) ^ ((tid >> 3) & 3);
  const _Float16* gB = Wc + (size_t)brow * DIM + bcg * 8;
  const int bdst = tid * 8;

#define STAGE_B(buf, k0)                                          \
  {                                                               \
    _Pragma("unroll") for (int i = 0; i < 2; ++i)                 \
        gl_lds16(gB + (size_t)i * 128 * DIM + (k0),               \
                 &Bl[buf][i * 4096 + bdst]);                      \
  }

  const int arow = tid >> 3;
  const int afc = (tid & 7) * 4;
  const float* gA = x + (size_t)(m0 + arow) * DIM + afc;
  const int awp = arow * 32 + ((((tid >> 1) & 3) ^ ((arow >> 1) & 3)) * 8) +
                  (tid & 1) * 4;

#define LOADX(rr, k0)                          \
  {                                            \
    rr = *(const float4*)(gA + (k0));          \
  }
#define CVT_WRITE_A(buf, rr)                                        \
  {                                                                 \
    f16x4 h = {(_Float16)rr.x, (_Float16)rr.y, (_Float16)rr.z,      \
               (_Float16)rr.w};                                     \
    *(f16x4*)&Al[buf][awp] = h;                                     \
  }

  f32x4 acc[2][4];
#pragma unroll
  for (int mi = 0; mi < 2; ++mi)
#pragma unroll
    for (int ni = 0; ni < 4; ++ni) acc[mi][ni] = (f32x4){0.f, 0.f, 0.f, 0.f};

  const int aswz = (fq ^ ((fm >> 1) & 3)) * 8;
  const int abase = (wm * 32 + fm) * 32 + aswz;
  const int bbase = (wn * 64 + fm) * 32 + aswz;

#define COMPUTE(cb)                                                     \
  {                                                                     \
    f16x8 afr[2], bfr[4];                                               \
    _Pragma("unroll") for (int mi = 0; mi < 2; ++mi)                    \
        afr[mi] = *(const f16x8*)&Al[cb][abase + mi * 16 * 32];         \
    _Pragma("unroll") for (int ni = 0; ni < 4; ++ni)                    \
        bfr[ni] = *(const f16x8*)&Bl[cb][bbase + ni * 16 * 32];         \
    _Pragma("unroll") for (int mi = 0; mi < 2; ++mi)                    \
        _Pragma("unroll") for (int ni = 0; ni < 4; ++ni)                \
            acc[mi][ni] = __builtin_amdgcn_mfma_f32_16x16x32_f16(       \
                afr[mi], bfr[ni], acc[mi][ni], 0, 0, 0);                \
  }

  float4 rE, rO;
  LOADX(rE, 0);
  STAGE_B(0, 0);
  LOADX(rO, 32);
  CVT_WRITE_A(0, rE);
  __syncthreads();

  for (int k2 = 0; k2 < 16; ++k2) {
    STAGE_B(1, (2 * k2 + 1) * 32);
    if (k2 < 15) LOADX(rE, (2 * k2 + 2) * 32);
    CVT_WRITE_A(1, rO);
    COMPUTE(0);
    __syncthreads();
    if (k2 < 15) {
      STAGE_B(0, (2 * k2 + 2) * 32);
      LOADX(rO, (2 * k2 + 3) * 32);
      CVT_WRITE_A(0, rE);
    }
    COMPUTE(1);
    __syncthreads();
  }
#undef STAGE_B
#undef LOADX
#undef CVT_WRITE_A
#undef COMPUTE

  // C/D: col = lane&15, row = (lane>>4)*4 + reg. Remap cols: v,ax interleaved.
#pragma unroll
  for (int mi = 0; mi < 2; ++mi)
#pragma unroll
    for (int ni = 0; ni < 4; ++ni) {
      const int gcol = wn * 64 + ni * 16 + fm;
      const int pcol = gcol < 128 ? gcol
                     : (gcol < 192 ? 128 + 2 * (gcol - 128) : 129 + 2 * (gcol - 192));
#pragma unroll
      for (int r = 0; r < 4; ++r) {
        const int grow = m0 + wm * 32 + mi * 16 + fq * 4 + r;
        projf[(size_t)grow * 256 + pcol] = acc[mi][ni][r];
      }
    }
}

// ---------------- Sequential scan v5: wave split + bulk chunk registers ----
// 128 blocks = (b, 16-row group rg), 512 threads = 8 waves.
// Staging: cooperative LDS ring (4 chunks x 8 steps x 256 f32; 512 threads
// stage 1 float4/chunk, 1.5 chunks ahead). NEW vs R5: both roles bulk-load a
// FULL 8-step chunk from LDS into registers at phase start (counted-lgkmcnt,
// one exposed ~latency per chunk), so the 8-step inner loops have ZERO
// memory ops -- the per-step ds_read latency exposure (R5's residual) is
// amortized 8x. {al,cc} handoff batched: 4x b128 write / read per chunk.
// Producer (waves 0-3): recurrence (R5 math; R1/R7 proved lookahead hurts).
// Consumer (waves 4-7): replays S one chunk behind, computes h, out, Sout.
__device__ __forceinline__ float red16(float x) {
  int v = __builtin_amdgcn_update_dpp(0, __float_as_int(x), 0xB1, 0xF, 0xF, true);
  x += __int_as_float(v);
  v = __builtin_amdgcn_update_dpp(0, __float_as_int(x), 0x4E, 0xF, 0xF, true);
  x += __int_as_float(v);
  v = __builtin_amdgcn_update_dpp(0, __float_as_int(x), 0x124, 0xF, 0xF, true);
  x += __int_as_float(v);
  v = __builtin_amdgcn_update_dpp(0, __float_as_int(x), 0x128, 0xF, 0xF, true);
  x += __int_as_float(v);
  return x;
}

__global__ __launch_bounds__(512, 1) void scan_kernel(
    const float* __restrict__ projf, const float* __restrict__ S0,
    const float* __restrict__ d_alpha, const float* __restrict__ b_alpha,
    float* __restrict__ out, float* __restrict__ Sout) {
  const int b = blockIdx.x >> 2;
  const int rg = blockIdx.x & 3;
  const int tid = threadIdx.x;
  const bool prod = tid < 256;
  const int ptid = tid & 255;
  const int c = ptid & 15;           // column lane
  const int lr = ptid >> 4;          // local row 0..15
  const int r = rg * 16 + lr;
  const int j0 = c * 4;

  __shared__ __align__(16) float lbuf[4][2048];    // 4-ring x (8 x 256) f32
  __shared__ __align__(16) float2 alcc[2][16][8];  // [buf][lr][si], 2 KB

  constexpr float NL2E = -1.44269504088896340736f;
  f32x2 s01, s23;
  {
    float4 v = *(const float4*)(S0 + ((size_t)b * NST + r) * NST + j0);
    s01 = (f32x2){v.x, v.y}; s23 = (f32x2){v.z, v.w};
  }
  const float da2 = d_alpha[r] * NL2E;
  const float ba2 = b_alpha[r] * NL2E;

  // staging: 512 threads x 1 float4 = one 8-step chunk (8 KB)
  const int sstep = tid >> 6;         // 0..7
  const int soff = (tid & 63) * 4;    // 0..252
  const int lidx = sstep * 256 + soff;
  const float* gp = projf + (size_t)b * 256;
#define GADDR(ch) (gp + (size_t)((ch) * 8 + sstep) * (BATCH * 256) + soff)

  float4 rA;
  rA = *(const float4*)GADDR(0); *(float4*)&lbuf[0][lidx] = rA;
  rA = *(const float4*)GADDR(1); *(float4*)&lbuf[1][lidx] = rA;
  rA = *(const float4*)GADDR(2);
  __syncthreads();

  for (int ch = 0; ch <= 64; ++ch) {
    if (prod) {
      if (ch < 64) {
        // ---- bulk LDS -> regs: whole chunk (8 x {k float4, va float2}) ----
        const float* Pb = &lbuf[ch & 3][0];
        float4 kP[8];
        float2 vP[8];
#pragma unroll
        for (int si = 0; si < 8; ++si) {
          kP[si] = *(const float4*)(Pb + si * 256 + j0);
          vP[si] = *(const float2*)(Pb + si * 256 + 128 + 2 * r);
        }
        float alv[8], ccv[8];
        // ---- pure-VALU 8-step recurrence ----
#pragma unroll
        for (int si = 0; si < 8; ++si) {
          const f32x2 k01 = {kP[si].x, kP[si].y};
          const f32x2 k23 = {kP[si].z, kP[si].w};
          f32x2 pa = s01 * k01 + s23 * k23;
          const float rr = red16(pa[0] + pa[1]);
          float z2 = fmaf(da2, rr, vP[si].y + ba2);
          z2 = __builtin_amdgcn_fmed3f(z2, -43.3f, 43.3f);
          const float e = __builtin_amdgcn_exp2f(z2);        // exp(-z)
          const float al = __builtin_amdgcn_rcpf(1.f + e);   // sigmoid(z)
          const float cc = (e * vP[si].x) * al;              // (1-al)*v
          const f32x2 al2 = {al, al}, cc2 = {cc, cc};
          s01 = al2 * s01 + cc2 * k01;
          s23 = al2 * s23 + cc2 * k23;
          alv[si] = al; ccv[si] = cc;
        }
        // ---- batched handoff: 4 x b128 ----
        if (c == 0) {
          float4 w0 = {alv[0], ccv[0], alv[1], ccv[1]};
          float4 w1 = {alv[2], ccv[2], alv[3], ccv[3]};
          float4 w2 = {alv[4], ccv[4], alv[5], ccv[5]};
          float4 w3 = {alv[6], ccv[6], alv[7], ccv[7]};
          float4* wp = (float4*)&alcc[ch & 1][lr][0];
          wp[0] = w0; wp[1] = w1; wp[2] = w2; wp[3] = w3;
        }
      }
    } else {
      if (ch >= 1) {
        const int pc = ch - 1;
        // ---- alcc first (oldest in lgkm FIFO -> counted wait skips rest) ----
        const float4* ap = (const float4*)&alcc[pc & 1][lr][0];
        float4 a0 = ap[0], a1 = ap[1], a2 = ap[2], a3 = ap[3];
        // ---- bulk LDS -> regs: whole chunk (8 x {k, q} float4) ----
        const float* Pb = &lbuf[pc & 3][0];
        float4 kC[8], qC[8];
#pragma unroll
        for (int si = 0; si < 8; ++si) {
          kC[si] = *(const float4*)(Pb + si * 256 + j0);
          qC[si] = *(const float4*)(Pb + si * 256 + 64 + j0);
        }
        float2 acv[8];
        acv[0] = make_float2(a0.x, a0.y); acv[1] = make_float2(a0.z, a0.w);
        acv[2] = make_float2(a1.x, a1.y); acv[3] = make_float2(a1.z, a1.w);
        acv[4] = make_float2(a2.x, a2.y); acv[5] = make_float2(a2.z, a2.w);
        acv[6] = make_float2(a3.x, a3.y); acv[7] = make_float2(a3.z, a3.w);
        // ---- pure-VALU 8-step replay + output ----
#pragma unroll
        for (int si = 0; si < 8; ++si) {
          const f32x2 k01 = {kC[si].x, kC[si].y};
          const f32x2 k23 = {kC[si].z, kC[si].w};
          const f32x2 al2 = {acv[si].x, acv[si].x};
          const f32x2 cc2 = {acv[si].y, acv[si].y};
          s01 = al2 * s01 + cc2 * k01;  // bit-identical S replay
          s23 = al2 * s23 + cc2 * k23;
          const f32x2 q01 = {qC[si].x, qC[si].y};
          const f32x2 q23 = {qC[si].z, qC[si].w};
          f32x2 hh = s01 * q01 + s23 * q23;
          const float h = red16(hh[0] + hh[1]);
          if (c == 0) {
            const float sg =
                __builtin_amdgcn_rcpf(1.f + __builtin_amdgcn_exp2f(h * NL2E));
            out[((size_t)(pc * 8 + si) * BATCH + b) * NST + r] = (h * h) * sg;
          }
        }
      }
    }
    __syncthreads();  // alcc handoff; lbuf readers of retiring slot done
    if (ch + 2 < 64) *(float4*)&lbuf[(ch + 2) & 3][lidx] = rA;
    if (ch + 3 < 64) rA = *(const float4*)GADDR(ch + 3);
    __syncthreads();  // staged chunk visible
  }
#undef GADDR

  if (!prod) {
    float4 o = {s01[0], s01[1], s23[0], s23[1]};
    *(float4*)(Sout + ((size_t)b * NST + r) * NST + j0) = o;
  }
}

extern "C" void kernel_launch(void* const* d_in, const int* in_sizes, int n_in,
                              void* d_out, int out_size, void* d_ws, size_t ws_size,
                              hipStream_t stream) {
  const float* x  = (const float*)d_in[0];
  const float* S0 = (const float*)d_in[1];
  const float* Wk = (const float*)d_in[2];
  const float* Wv = (const float*)d_in[3];
  const float* Wq = (const float*)d_in[4];
  const float* Wa = (const float*)d_in[5];
  const float* da = (const float*)d_in[6];
  const float* ba = (const float*)d_in[7];

  float* out  = (float*)d_out;                        // [T,B,64]
  float* Sout = out + (size_t)T_STEPS * BATCH * NST;  // [B,64,64]
  float* projf = (float*)d_ws;                        // [16384][256] f32 = 16 MB
  _Float16* Wc = (_Float16*)((char*)d_ws + (size_t)16384 * 256 * 4);  // 512 KB

  wconv<<<256, 256, 0, stream>>>(Wk, Wv, Wq, Wa, Wc);
  proj_gemm<<<256, 512, 0, stream>>>(x, Wc, projf);
  scan_kernel<<<4 * BATCH, 512, 0, stream>>>(projf, S0, da, ba, out, Sout);
}

// Round 9
// 197.078 us; speedup vs baseline: 1.2059x; 1.0506x over previous
//
#include <hip/hip_runtime.h>
#include <hip/hip_bf16.h>

#define T_STEPS 512
#define BATCH 32
#define NST 64
#define DIM 1024

typedef _Float16 f16x8 __attribute__((ext_vector_type(8)));
typedef _Float16 f16x4 __attribute__((ext_vector_type(4)));
typedef float f32x4 __attribute__((ext_vector_type(4)));
typedef float f32x2 __attribute__((ext_vector_type(2)));

__device__ __forceinline__ void gl_lds16(const void* g, void* l) {
  __builtin_amdgcn_global_load_lds(
      (const __attribute__((address_space(1))) void*)g,
      (__attribute__((address_space(3))) void*)l, 16, 0, 0);
}

// ---------------- W concat + fp16 convert ----------------
// Wc[256][1024] fp16, row order [Wk | Wq | Wv | Wa]. Wa pre-scaled by -log2(e)
// so the scan's sigmoid can use exp2 directly.
__global__ __launch_bounds__(256) void wconv(
    const float* __restrict__ Wk, const float* __restrict__ Wv,
    const float* __restrict__ Wq, const float* __restrict__ Wa,
    _Float16* __restrict__ Wc) {
  const int n = blockIdx.x;
  const int g = n >> 6, r = n & 63;
  const float* W = (g == 0) ? Wk : (g == 1) ? Wq : (g == 2) ? Wv : Wa;
  const float sc = (g == 3) ? -1.44269504088896340736f : 1.0f;
  float4 v = *(const float4*)(W + (size_t)r * DIM + threadIdx.x * 4);
  f16x4 h = {(_Float16)(v.x * sc), (_Float16)(v.y * sc), (_Float16)(v.z * sc),
             (_Float16)(v.w * sc)};
  *(f16x4*)(Wc + (size_t)n * DIM + threadIdx.x * 4) = h;
}

// ---------------- Projection GEMM v2 (fp32 output) ----------------
// BM=64, BN=256 (full width -> x read ONCE), BK=32.
// 256 blocks (1/CU), 512 threads = 8 waves (2/SIMD), wave grid 2m x 4n,
// wave tile 32m x 64n. A and B double-buffered in LDS, ONE barrier/K-step.
// projf[m][256] fp32, cols [k(64) | q(64) | v,ax interleaved(128)].
__global__ __launch_bounds__(512) void proj_gemm(
    const float* __restrict__ x, const _Float16* __restrict__ Wc,
    float* __restrict__ projf) {
  const int m0 = blockIdx.x * 64;
  const int tid = threadIdx.x;
  const int lane = tid & 63, wv = tid >> 6;
  const int wm = wv >> 2, wn = wv & 3;
  const int fm = lane & 15, fq = lane >> 4;

  __shared__ __align__(16) _Float16 Bl[2][256 * 32];  // 2 x 16 KB
  __shared__ __align__(16) _Float16 Al[2][64 * 32];   // 2 x 4 KB

  const int brow = tid >> 2;
  const int bcg = (tid & 3) ^ ((tid >> 3) & 3);
  const _Float16* gB = Wc + (size_t)brow * DIM + bcg * 8;
  const int bdst = tid * 8;

#define STAGE_B(buf, k0)                                          \
  {                                                               \
    _Pragma("unroll") for (int i = 0; i < 2; ++i)                 \
        gl_lds16(gB + (size_t)i * 128 * DIM + (k0),               \
                 &Bl[buf][i * 4096 + bdst]);                      \
  }

  const int arow = tid >> 3;
  const int afc = (tid & 7) * 4;
  const float* gA = x + (size_t)(m0 + arow) * DIM + afc;
  const int awp = arow * 32 + ((((tid >> 1) & 3) ^ ((arow >> 1) & 3)) * 8) +
                  (tid & 1) * 4;

#define LOADX(rr, k0)                          \
  {                                            \
    rr = *(const float4*)(gA + (k0));          \
  }
#define CVT_WRITE_A(buf, rr)                                        \
  {                                                                 \
    f16x4 h = {(_Float16)rr.x, (_Float16)rr.y, (_Float16)rr.z,      \
               (_Float16)rr.w};                                     \
    *(f16x4*)&Al[buf][awp] = h;                                     \
  }

  f32x4 acc[2][4];
#pragma unroll
  for (int mi = 0; mi < 2; ++mi)
#pragma unroll
    for (int ni = 0; ni < 4; ++ni) acc[mi][ni] = (f32x4){0.f, 0.f, 0.f, 0.f};

  const int aswz = (fq ^ ((fm >> 1) & 3)) * 8;
  const int abase = (wm * 32 + fm) * 32 + aswz;
  const int bbase = (wn * 64 + fm) * 32 + aswz;

#define COMPUTE(cb)                                                     \
  {                                                                     \
    f16x8 afr[2], bfr[4];                                               \
    _Pragma("unroll") for (int mi = 0; mi < 2; ++mi)                    \
        afr[mi] = *(const f16x8*)&Al[cb][abase + mi * 16 * 32];         \
    _Pragma("unroll") for (int ni = 0; ni < 4; ++ni)                    \
        bfr[ni] = *(const f16x8*)&Bl[cb][bbase + ni * 16 * 32];         \
    _Pragma("unroll") for (int mi = 0; mi < 2; ++mi)                    \
        _Pragma("unroll") for (int ni = 0; ni < 4; ++ni)                \
            acc[mi][ni] = __builtin_amdgcn_mfma_f32_16x16x32_f16(       \
                afr[mi], bfr[ni], acc[mi][ni], 0, 0, 0);                \
  }

  float4 rE, rO;
  LOADX(rE, 0);
  STAGE_B(0, 0);
  LOADX(rO, 32);
  CVT_WRITE_A(0, rE);
  __syncthreads();

  for (int k2 = 0; k2 < 16; ++k2) {
    STAGE_B(1, (2 * k2 + 1) * 32);
    if (k2 < 15) LOADX(rE, (2 * k2 + 2) * 32);
    CVT_WRITE_A(1, rO);
    COMPUTE(0);
    __syncthreads();
    if (k2 < 15) {
      STAGE_B(0, (2 * k2 + 2) * 32);
      LOADX(rO, (2 * k2 + 3) * 32);
      CVT_WRITE_A(0, rE);
    }
    COMPUTE(1);
    __syncthreads();
  }
#undef STAGE_B
#undef LOADX
#undef CVT_WRITE_A
#undef COMPUTE

  // C/D: col = lane&15, row = (lane>>4)*4 + reg. Remap cols: v,ax interleaved.
#pragma unroll
  for (int mi = 0; mi < 2; ++mi)
#pragma unroll
    for (int ni = 0; ni < 4; ++ni) {
      const int gcol = wn * 64 + ni * 16 + fm;
      const int pcol = gcol < 128 ? gcol
                     : (gcol < 192 ? 128 + 2 * (gcol - 128) : 129 + 2 * (gcol - 192));
#pragma unroll
      for (int r = 0; r < 4; ++r) {
        const int grow = m0 + wm * 32 + mi * 16 + fq * 4 + r;
        projf[(size_t)grow * 256 + pcol] = acc[mi][ni][r];
      }
    }
}

// ---------------- Sequential scan v6: ONE barrier per chunk ----------------
// 128 blocks = (b, 16-row group rg), 512 threads = 8 waves (prod 0-3, cons 4-7).
// All VMEM is issued at the TOP of each iteration so hipcc's forced
// vmcnt(0)-before-s_barrier drain has the whole chunk compute (~1500 cyc) as
// slack: (1) global load of chunk ch+2 -> reg; (2) consumer's deferred out
// stores for chunk ch-2. Single barrier per chunk; the lbuf ds_write happens
// POST-barrier (safety: old slot content last read 2 barriers earlier;
// visibility: first read 1 barrier later -- both verified).
// Producer: 8-step recurrence, bulk LDS->reg, {al,cc} -> alcc ring.
// Consumer: replays S one chunk behind, h = S.q, y kept in regs, stored next
// iteration.
__device__ __forceinline__ float red16(float x) {
  int v = __builtin_amdgcn_update_dpp(0, __float_as_int(x), 0xB1, 0xF, 0xF, true);
  x += __int_as_float(v);
  v = __builtin_amdgcn_update_dpp(0, __float_as_int(x), 0x4E, 0xF, 0xF, true);
  x += __int_as_float(v);
  v = __builtin_amdgcn_update_dpp(0, __float_as_int(x), 0x124, 0xF, 0xF, true);
  x += __int_as_float(v);
  v = __builtin_amdgcn_update_dpp(0, __float_as_int(x), 0x128, 0xF, 0xF, true);
  x += __int_as_float(v);
  return x;
}

__global__ __launch_bounds__(512, 1) void scan_kernel(
    const float* __restrict__ projf, const float* __restrict__ S0,
    const float* __restrict__ d_alpha, const float* __restrict__ b_alpha,
    float* __restrict__ out, float* __restrict__ Sout) {
  const int b = blockIdx.x >> 2;
  const int rg = blockIdx.x & 3;
  const int tid = threadIdx.x;
  const bool prod = tid < 256;
  const int ptid = tid & 255;
  const int c = ptid & 15;           // column lane
  const int lr = ptid >> 4;          // local row 0..15
  const int r = rg * 16 + lr;
  const int j0 = c * 4;

  __shared__ __align__(16) float lbuf[4][2048];    // 4-ring x (8 x 256) f32
  __shared__ __align__(16) float2 alcc[2][16][8];  // [buf][lr][si], 2 KB

  constexpr float NL2E = -1.44269504088896340736f;
  f32x2 s01, s23;
  {
    float4 v = *(const float4*)(S0 + ((size_t)b * NST + r) * NST + j0);
    s01 = (f32x2){v.x, v.y}; s23 = (f32x2){v.z, v.w};
  }
  const float da2 = d_alpha[r] * NL2E;
  const float ba2 = b_alpha[r] * NL2E;

  // staging: 512 threads x 1 float4 = one 8-step chunk (8 KB)
  const int sstep = tid >> 6;         // 0..7
  const int soff = (tid & 63) * 4;    // 0..252
  const int lidx = sstep * 256 + soff;
  const float* gp = projf + (size_t)b * 256;
#define GADDR(ch) (gp + (size_t)((ch) * 8 + sstep) * (BATCH * 256) + soff)

  // prologue: stage chunks 0, 1
  float4 rA;
  rA = *(const float4*)GADDR(0); *(float4*)&lbuf[0][lidx] = rA;
  rA = *(const float4*)GADDR(1); *(float4*)&lbuf[1][lidx] = rA;
  __syncthreads();

  float ys[8];  // consumer: pending gated outputs (chunk ch-1 after iter ch)

  for (int ch = 0; ch <= 64; ++ch) {
    // ---- issue-early VMEM: full chunk compute of slack before the barrier --
    if (ch + 2 < 64) rA = *(const float4*)GADDR(ch + 2);

    if (prod) {
      if (ch < 64) {
        // bulk LDS -> regs: whole chunk (8 x {k float4, va float2})
        const float* Pb = &lbuf[ch & 3][0];
        float4 kP[8];
        float2 vP[8];
#pragma unroll
        for (int si = 0; si < 8; ++si) {
          kP[si] = *(const float4*)(Pb + si * 256 + j0);
          vP[si] = *(const float2*)(Pb + si * 256 + 128 + 2 * r);
        }
        float alv[8], ccv[8];
#pragma unroll
        for (int si = 0; si < 8; ++si) {
          const f32x2 k01 = {kP[si].x, kP[si].y};
          const f32x2 k23 = {kP[si].z, kP[si].w};
          f32x2 pa = s01 * k01 + s23 * k23;
          const float rr = red16(pa[0] + pa[1]);
          float z2 = fmaf(da2, rr, vP[si].y + ba2);
          z2 = __builtin_amdgcn_fmed3f(z2, -43.3f, 43.3f);
          const float e = __builtin_amdgcn_exp2f(z2);        // exp(-z)
          const float al = __builtin_amdgcn_rcpf(1.f + e);   // sigmoid(z)
          const float cc = (e * vP[si].x) * al;              // (1-al)*v
          const f32x2 al2 = {al, al}, cc2 = {cc, cc};
          s01 = al2 * s01 + cc2 * k01;
          s23 = al2 * s23 + cc2 * k23;
          alv[si] = al; ccv[si] = cc;
        }
        if (c == 0) {  // batched handoff: 4 x b128
          float4 w0 = {alv[0], ccv[0], alv[1], ccv[1]};
          float4 w1 = {alv[2], ccv[2], alv[3], ccv[3]};
          float4 w2 = {alv[4], ccv[4], alv[5], ccv[5]};
          float4 w3 = {alv[6], ccv[6], alv[7], ccv[7]};
          float4* wp = (float4*)&alcc[ch & 1][lr][0];
          wp[0] = w0; wp[1] = w1; wp[2] = w2; wp[3] = w3;
        }
      }
    } else {
      // deferred out stores for chunk ch-2 (computed last iteration)
      if (ch >= 2 && c == 0) {
#pragma unroll
        for (int si = 0; si < 8; ++si)
          out[((size_t)((ch - 2) * 8 + si) * BATCH + b) * NST + r] = ys[si];
      }
      if (ch >= 1) {
        const int pc = ch - 1;
        // alcc first (oldest in lgkm FIFO)
        const float4* ap = (const float4*)&alcc[pc & 1][lr][0];
        float4 a0 = ap[0], a1 = ap[1], a2 = ap[2], a3 = ap[3];
        const float* Pb = &lbuf[pc & 3][0];
        float4 kC[8], qC[8];
#pragma unroll
        for (int si = 0; si < 8; ++si) {
          kC[si] = *(const float4*)(Pb + si * 256 + j0);
          qC[si] = *(const float4*)(Pb + si * 256 + 64 + j0);
        }
        float2 acv[8];
        acv[0] = make_float2(a0.x, a0.y); acv[1] = make_float2(a0.z, a0.w);
        acv[2] = make_float2(a1.x, a1.y); acv[3] = make_float2(a1.z, a1.w);
        acv[4] = make_float2(a2.x, a2.y); acv[5] = make_float2(a2.z, a2.w);
        acv[6] = make_float2(a3.x, a3.y); acv[7] = make_float2(a3.z, a3.w);
#pragma unroll
        for (int si = 0; si < 8; ++si) {
          const f32x2 k01 = {kC[si].x, kC[si].y};
          const f32x2 k23 = {kC[si].z, kC[si].w};
          const f32x2 al2 = {acv[si].x, acv[si].x};
          const f32x2 cc2 = {acv[si].y, acv[si].y};
          s01 = al2 * s01 + cc2 * k01;  // bit-identical S replay
          s23 = al2 * s23 + cc2 * k23;
          const f32x2 q01 = {qC[si].x, qC[si].y};
          const f32x2 q23 = {qC[si].z, qC[si].w};
          f32x2 hh = s01 * q01 + s23 * q23;
          const float h = red16(hh[0] + hh[1]);
          const float sg =
              __builtin_amdgcn_rcpf(1.f + __builtin_amdgcn_exp2f(h * NL2E));
          ys[si] = (h * h) * sg;  // store deferred to next iteration
        }
      }
    }

    __syncthreads();  // single barrier: vmcnt(0)/lgkmcnt(0) all pre-covered
    // post-barrier staging write; visible to readers via NEXT iter's barrier
    if (ch + 2 < 64) *(float4*)&lbuf[(ch + 2) & 3][lidx] = rA;
  }
#undef GADDR

  if (!prod) {
    if (c == 0) {  // chunk 63's outputs (computed at iter 64)
#pragma unroll
      for (int si = 0; si < 8; ++si)
        out[((size_t)(63 * 8 + si) * BATCH + b) * NST + r] = ys[si];
    }
    float4 o = {s01[0], s01[1], s23[0], s23[1]};
    *(float4*)(Sout + ((size_t)b * NST + r) * NST + j0) = o;
  }
}

extern "C" void kernel_launch(void* const* d_in, const int* in_sizes, int n_in,
                              void* d_out, int out_size, void* d_ws, size_t ws_size,
                              hipStream_t stream) {
  const float* x  = (const float*)d_in[0];
  const float* S0 = (const float*)d_in[1];
  const float* Wk = (const float*)d_in[2];
  const float* Wv = (const float*)d_in[3];
  const float* Wq = (const float*)d_in[4];
  const float* Wa = (const float*)d_in[5];
  const float* da = (const float*)d_in[6];
  const float* ba = (const float*)d_in[7];

  float* out  = (float*)d_out;                        // [T,B,64]
  float* Sout = out + (size_t)T_STEPS * BATCH * NST;  // [B,64,64]
  float* projf = (float*)d_ws;                        // [16384][256] f32 = 16 MB
  _Float16* Wc = (_Float16*)((char*)d_ws + (size_t)16384 * 256 * 4);  // 512 KB

  wconv<<<256, 256, 0, stream>>>(Wk, Wv, Wq, Wa, Wc);
  proj_gemm<<<256, 512, 0, stream>>>(x, Wc, projf);
  scan_kernel<<<4 * BATCH, 512, 0, stream>>>(projf, S0, da, ba, out, Sout);
}